// Round 13
// baseline (704.056 us; speedup 1.0000x reference)
//
#include <hip/hip_runtime.h>
#include <math.h>

// ---- types ----------------------------------------------------------------
typedef __attribute__((ext_vector_type(8))) __bf16 bf16x8;   // MFMA A/B frag (4 VGPR)
typedef __attribute__((ext_vector_type(8))) short  short8;   // raw 16B store
typedef __attribute__((ext_vector_type(4))) unsigned short ushort4v;
typedef __attribute__((ext_vector_type(4))) float  floatx4;  // 16x16 C/D frag
typedef __attribute__((ext_vector_type(16))) float floatx16; // 32x32 C/D frag

typedef __attribute__((address_space(1))) unsigned int as1_u32;
typedef __attribute__((address_space(3))) unsigned int as3_u32;

// async global->LDS, 16B per lane, dest = uniform base + lane*16 (GEMM only)
__device__ __forceinline__ void async_copy16(const void* g, void* l) {
  __builtin_amdgcn_global_load_lds((const as1_u32*)g, (as3_u32*)l, 16, 0, 0);
}

__device__ __forceinline__ unsigned short f2bf(float f) {  // RNE float->bf16 bits
  union { float f; unsigned u; } v; v.f = f;
  unsigned r = v.u + 0x7fffu + ((v.u >> 16) & 1u);
  return (unsigned short)(r >> 16);
}

__device__ __forceinline__ floatx4 mfma_bf16(bf16x8 a, bf16x8 b, floatx4 c) {
  return __builtin_amdgcn_mfma_f32_16x16x32_bf16(a, b, c, 0, 0, 0);
}

__device__ __forceinline__ floatx16 mfma32(bf16x8 a, bf16x8 b, floatx16 c) {
  return __builtin_amdgcn_mfma_f32_32x32x16_bf16(a, b, c, 0, 0, 0);
}

__device__ __forceinline__ bf16x8 lds_frag(const unsigned short* p) {
  return *(const bf16x8*)(const void*)p;  // ds_read_b128
}

__device__ __forceinline__ bf16x8 g_frag(const unsigned short* p) {
  return *(const bf16x8*)(const void*)p;  // global_load_dwordx4
}

// ---- prep: all four f32->bf16 conversions in ONE launch --------------------
__global__ __launch_bounds__(256)
void prep(const float* __restrict__ x,  const float* __restrict__ wq,
          const float* __restrict__ wk, const float* __restrict__ wv,
          unsigned short* __restrict__ Xb, unsigned short* __restrict__ Wqb,
          unsigned short* __restrict__ Wkb, unsigned short* __restrict__ Wvb) {
  const int i = blockIdx.x * 256 + threadIdx.x;
  const float* s; unsigned short* d; int off;
  if (i < 2097152)             { s = x;  d = Xb;  off = i; }
  else if (i < 2097152+65536)  { s = wq; d = Wqb; off = i - 2097152; }
  else if (i < 2097152+131072) { s = wk; d = Wkb; off = i - (2097152+65536); }
  else                         { s = wv; d = Wvb; off = i - (2097152+131072); }
  const float4 v = ((const float4*)s)[off];
  ushort4v o;
  o.x = f2bf(v.x); o.y = f2bf(v.y); o.z = f2bf(v.z); o.w = f2bf(v.w);
  *(ushort4v*)(void*)(d + (size_t)off * 4) = o;
}

// ---- fused QKV GEMM: unchanged (verified) ----------------------------------
__global__ __launch_bounds__(256, 2)
void gemm_qkv(const unsigned short* __restrict__ Xb,
              const unsigned short* __restrict__ Wqb,
              const unsigned short* __restrict__ Wkb,
              const unsigned short* __restrict__ Wvb,
              unsigned short* __restrict__ Q,
              unsigned short* __restrict__ K,
              unsigned short* __restrict__ Vt) {
  const int gid = blockIdx.x;
  const unsigned short *A, *B; unsigned short* C;
  int m0, n0, N;
  if (gid < 512) {                        // Q = Xb · Wq^T
    A = Xb; B = Wqb; C = Q; N = 512;
    m0 = (gid & 127) * 128; n0 = (gid >> 7) * 128;
  } else if (gid < 1024) {                // K = Xb · Wk^T
    A = Xb; B = Wkb; C = K; N = 512;
    m0 = ((gid - 512) & 127) * 128; n0 = ((gid - 512) >> 7) * 128;
  } else {                                // V^T = Wv · Xb^T  (M=512, N=16384)
    A = Wvb; B = Xb; C = Vt; N = 16384;
    m0 = ((gid - 1024) & 3) * 128; n0 = ((gid - 1024) >> 2) * 128;
  }

  __shared__ unsigned short As[128 * 64];
  __shared__ unsigned short Bs[128 * 64];
  const int tid = threadIdx.x;
  const int w = tid >> 6, lane = tid & 63;
  const int quad = lane >> 4, l15 = lane & 15;
  const int wm = w >> 1, wn = w & 1;
  const int row_l = lane >> 3;
  const int chk   = lane & 7;
  const int s_chk = chk ^ row_l;          // swizzled SOURCE chunk

  floatx4 acc[16];
#pragma unroll
  for (int i = 0; i < 16; i++) acc[i] = (floatx4){0.f, 0.f, 0.f, 0.f};

  for (int kt = 0; kt < 8; kt++) {
    __syncthreads();
#pragma unroll
    for (int i = 0; i < 4; i++) {
      const int c = w * 4 + i;
      const int row = c * 8 + row_l;
      async_copy16(A + (size_t)(m0 + row) * 512 + kt * 64 + s_chk * 8, &As[c * 512]);
      async_copy16(B + (size_t)(n0 + row) * 512 + kt * 64 + s_chk * 8, &Bs[c * 512]);
    }
    __syncthreads();
#pragma unroll
    for (int kc = 0; kc < 2; kc++) {
      bf16x8 af[4], bfv[4];
#pragma unroll
      for (int i = 0; i < 4; i++) {
        const int pc = ((kc * 4 + quad) ^ (l15 & 7)) * 8;
        af[i]  = lds_frag(&As[(wm * 64 + i * 16 + l15) * 64 + pc]);
        bfv[i] = lds_frag(&Bs[(wn * 64 + i * 16 + l15) * 64 + pc]);
      }
#pragma unroll
      for (int mi = 0; mi < 4; mi++)
#pragma unroll
        for (int ni = 0; ni < 4; ni++)
          acc[mi * 4 + ni] = mfma_bf16(af[mi], bfv[ni], acc[mi * 4 + ni]);
    }
  }
#pragma unroll
  for (int mi = 0; mi < 4; mi++)
#pragma unroll
    for (int ni = 0; ni < 4; ni++)
#pragma unroll
      for (int r = 0; r < 4; r++) {
        const int row = m0 + wm * 64 + mi * 16 + quad * 4 + r;
        const int col = n0 + wn * 64 + ni * 16 + l15;
        C[(size_t)row * N + col] = f2bf(acc[mi * 4 + ni][r]);
      }
}

// ---- fused attention: NO K/V LDS STAGING (round 13 = round 12, resubmitted
// after infra timeout; kernel never ran) -------------------------------------
// Evidence: R4 (730 KB LDS/step) == R9 (488 KB) == ~9000 cyc/step; R11
// (2 blocks/CU) WORSE -> the CU-shared LDS data port is the critical path.
// Guide m169: don't LDS-stage what L2 fits. Each XCD's 32 blocks share one
// batch (XCD swizzle); hot K/V per step = 128 KB, L2-resident. The MFMA
// B-operand fragment is 16 CONTIGUOUS bytes per lane in both K (row-major:
// 8 consecutive feats of key lane&31) and Vt (8 consecutive keys of d row
// lane&31) -> load fragments directly global->VGPR (same gather pattern as
// the verified Q loads). Ks/Vs/DMA/drains/swizzles deleted; LDS keeps only
// Sx/Pb/m/l/a (~26 KB). 3 barriers/step. Fragment loads double-buffered
// 4-deep; compiler inserts precise vmcnt. Arithmetic (dual sa/sb chains,
// MFMA order, softmax, PV order) BIT-IDENTICAL to R9 -> absmax oracle
// = 4.88e-4 exactly.
#define SCALE 0.044194173824159216f  // 1/sqrt(512)

__global__ __launch_bounds__(512, 1)
void attn_kernel(const unsigned short* __restrict__ Qg,
                 const unsigned short* __restrict__ Kg,
                 const unsigned short* __restrict__ Vt,   // [512][16384] = V^T
                 float* __restrict__ O) {                 // f32 output
  __shared__ float Sx[64][65];              // 16.6 KB
  __shared__ unsigned short Pb[64 * 64];    //  8 KB (XOR-swizzled rows)
  __shared__ float m_row[64], l_row[64], a_row[64];

  const int tid = threadIdx.x;
  const int w = tid >> 6, lane = tid & 63;
  const int l31 = lane & 31, lh = lane >> 5, l7 = lane & 7;

  // XCD-contiguous swizzle: each XCD gets 32 consecutive logical blocks
  const int g0 = blockIdx.x;
  const int g  = (g0 & 7) * 32 + (g0 >> 3);   // 256 blocks, bijective
  const int b  = g >> 6;
  const int q0 = (g & 63) * 64;

  if (tid < 64) { m_row[tid] = -3.0e38f; l_row[tid] = 0.f; }

  const int t  = w & 3;          // phase-1 tile: q-half t>>1, key-half t&1
  const int gk = w >> 2;         // phase-1 feature-half
  const int p2 = w >> 2, dbase = (w & 3) * 128;  // phase-3 roles (R9)

  // Q A-fragments: 32 q-rows x 256 feats per wave (64 VGPR; R9 verbatim)
  bf16x8 qf[16];
  {
    const unsigned short* qrow =
        Qg + (size_t)(b * 4096 + q0 + (t >> 1) * 32 + l31) * 512;
#pragma unroll
    for (int i = 0; i < 16; i++)
      qf[i] = g_frag(qrow + gk * 256 + i * 16 + lh * 8);
  }

  floatx16 oacc[4];   // 4 d-tiles of 32x32 per wave: 32q x 128d
#pragma unroll
  for (int j = 0; j < 4; j++)
#pragma unroll
    for (int r = 0; r < 16; r++) oacc[j][r] = 0.f;

  // Per-lane fragment bases (16B-contiguous per lane):
  // K-frag (i): key = kt*64 + (t&1)*32 + l31; feats gk*256 + i*16 + lh*8 ..+7
  const unsigned short* kfb = Kg + (size_t)b * 4096 * 512
      + (size_t)((t & 1) * 32 + l31) * 512 + gk * 256 + lh * 8;
  // V-frag (j,kk): d = dbase + j*32 + l31; keys kt*64 + kk*16 + lh*8 ..+7
  const unsigned short* vfb = Vt + (size_t)b * 4096
      + (size_t)(dbase + l31) * 16384 + lh * 8;

  const int srow = tid >> 3, sg = tid & 7;
  const int pb_wchunk = sg ^ (srow & 7);   // Pb write swizzle (R9-verified)

  for (int kt = 0; kt < 64; kt++) {
    // ---- phase 1: partial S-tile 32q x 32k over 256 feats, K-frags from
    //      global (L2), dual acc chains (R9 bit-identical order)
    {
      floatx16 sa, sb;
#pragma unroll
      for (int r = 0; r < 16; r++) { sa[r] = 0.f; sb[r] = 0.f; }
      const unsigned short* kp = kfb + (size_t)kt * (64 * 512);
      bf16x8 kf[4];
#pragma unroll
      for (int i = 0; i < 4; i++) kf[i] = g_frag(kp + i * 16);
#pragma unroll
      for (int i = 0; i < 16; i += 2) {
        bf16x8 c0 = kf[i & 3];
        bf16x8 c1 = kf[(i + 1) & 3];
        if (i + 4 < 16) kf[i & 3]       = g_frag(kp + (i + 4) * 16);
        if (i + 5 < 16) kf[(i + 1) & 3] = g_frag(kp + (i + 5) * 16);
        sa = mfma32(qf[i], c0, sa);
        sb = mfma32(qf[i + 1], c1, sb);
      }
#pragma unroll
      for (int r = 0; r < 16; r++) sa[r] += sb[r];

      if (w < 4) {   // writer half: raw partial (R9 verbatim)
#pragma unroll
        for (int reg = 0; reg < 16; reg++) {
          const int rl = (reg & 3) + 8 * (reg >> 2) + 4 * lh;
          Sx[(t >> 1) * 32 + rl][(t & 1) * 32 + l31] = sa[reg];
        }
      }
      __syncthreads();   // B2a: writer partials visible
      if (w >= 4) {      // adder half: exclusive-ownership add + scale (R9)
#pragma unroll
        for (int reg = 0; reg < 16; reg++) {
          const int rl = (reg & 3) + 8 * (reg >> 2) + 4 * lh;
          float* p = &Sx[(t >> 1) * 32 + rl][(t & 1) * 32 + l31];
          *p = (*p + sa[reg]) * SCALE;
        }
      }
    }
    __syncthreads();   // B2b: Sx final

    // ---- phase 2: online softmax (fp32), 8 lanes per q-row (R9 verbatim)
    {
      float vals[8];
      float tmax = -3.0e38f;
#pragma unroll
      for (int j = 0; j < 8; j++) {
        float xv = Sx[srow][sg * 8 + j];
        xv = fminf(fmaxf(xv, -1.0e4f), 1.0e4f);
        vals[j] = xv;
        tmax = fmaxf(tmax, xv);
      }
      tmax = fmaxf(tmax, __shfl_xor(tmax, 1));
      tmax = fmaxf(tmax, __shfl_xor(tmax, 2));
      tmax = fmaxf(tmax, __shfl_xor(tmax, 4));
      const float m_old = m_row[srow];
      const float m_new = fmaxf(m_old, tmax);
      const float alpha = __expf(m_old - m_new);
      float lsum = 0.f;
      short8 pvec;
#pragma unroll
      for (int j = 0; j < 8; j++) {
        const float p = __expf(vals[j] - m_new);
        lsum += p;
        pvec[j] = (short)f2bf(p);
      }
      lsum += __shfl_xor(lsum, 1);
      lsum += __shfl_xor(lsum, 2);
      lsum += __shfl_xor(lsum, 4);
      *(short8*)(void*)&Pb[srow * 64 + pb_wchunk * 8] = pvec;
      if (sg == 0) {
        m_row[srow] = m_new;
        l_row[srow] = l_row[srow] * alpha + lsum;
        a_row[srow] = alpha;
      }
    }
    __syncthreads();        // B3: Pb, a_row visible

    // ---- pre-PV: O-rescale + P A-fragments from Pb (R9 verbatim)
#pragma unroll
    for (int reg = 0; reg < 16; reg++) {
      const float a = a_row[p2 * 32 + (reg & 3) + 8 * (reg >> 2) + 4 * lh];
#pragma unroll
      for (int j = 0; j < 4; j++) oacc[j][reg] *= a;
    }
    bf16x8 pfr[4];
    {
      const int q = p2 * 32 + l31;   // q&7 == l7
#pragma unroll
      for (int kk = 0; kk < 4; kk++)
        pfr[kk] = lds_frag(&Pb[q * 64 + (((kk * 2 + lh) ^ l7) * 8)]);
    }

    // ---- phase 3: O += P V, V-frags from global (L2), 16 MFMA(32x32x16)
    //      flattened (j,kk), R9 accumulation order preserved
    {
      const unsigned short* vp = vfb + kt * 64;
      bf16x8 vf[4];
#pragma unroll
      for (int u = 0; u < 4; u++) vf[u] = g_frag(vp + u * 16);
#pragma unroll
      for (int u = 0; u < 16; u++) {
        bf16x8 cur = vf[u & 3];
        if (u + 4 < 16) {
          const int un = u + 4;
          vf[u & 3] = g_frag(vp + (size_t)(un >> 2) * (32 * 16384) + (un & 3) * 16);
        }
        oacc[u >> 2] = mfma32(pfr[u & 3], cur, oacc[u >> 2]);
      }
    }
  }

  // ---- epilogue: O / l, f32 store (R9 verbatim)
  __syncthreads();
#pragma unroll
  for (int reg = 0; reg < 16; reg++) {
    const int rl = (reg & 3) + 8 * (reg >> 2) + 4 * lh;
    const float inv = 1.0f / l_row[p2 * 32 + rl];
    const int row = b * 4096 + q0 + p2 * 32 + rl;
#pragma unroll
    for (int j = 0; j < 4; j++)
      O[(size_t)row * 512 + dbase + j * 32 + l31] = oacc[j][reg] * inv;
  }
}

// ---- launch ---------------------------------------------------------------
extern "C" void kernel_launch(void* const* d_in, const int* in_sizes, int n_in,
                              void* d_out, int out_size, void* d_ws, size_t ws_size,
                              hipStream_t stream) {
  const float* x   = (const float*)d_in[0];
  const float* wqf = (const float*)d_in[1];
  const float* wkf = (const float*)d_in[2];
  const float* wvf = (const float*)d_in[3];

  unsigned short* Xb  = (unsigned short*)d_out;        // 16384 x 512 bf16 (dead before attn)
  unsigned short* Wqb = (unsigned short*)d_ws;         // 512 x 512
  unsigned short* Wkb = Wqb + (size_t)512 * 512;
  unsigned short* Wvb = Wkb + (size_t)512 * 512;
  unsigned short* Q   = Wvb + (size_t)512 * 512;       // 16384 x 512
  unsigned short* K   = Q + (size_t)16384 * 512;       // 16384 x 512
  unsigned short* Vt  = K + (size_t)16384 * 512;       // 512 x 16384 (V^T)

  prep<<<dim3(8960), 256, 0, stream>>>(x, wqf, wkf, wvf, Xb, Wqb, Wkb, Wvb);
  gemm_qkv<<<dim3(1536), 256, 0, stream>>>(Xb, Wqb, Wkb, Wvb, Q, K, Vt);
  attn_kernel<<<dim3(256), 512, 0, stream>>>(Q, K, Vt, (float*)d_out);
}

// Round 15
// 474.106 us; speedup vs baseline: 1.4850x; 1.4850x over previous
//
#include <hip/hip_runtime.h>
#include <math.h>

// ---- types ----------------------------------------------------------------
typedef __attribute__((ext_vector_type(8))) __bf16 bf16x8;   // MFMA A/B frag (4 VGPR)
typedef __attribute__((ext_vector_type(8))) short  short8;   // raw 16B store
typedef __attribute__((ext_vector_type(4))) unsigned short ushort4v;
typedef __attribute__((ext_vector_type(4))) float  floatx4;  // 16x16 C/D frag
typedef __attribute__((ext_vector_type(16))) float floatx16; // 32x32 C/D frag

typedef __attribute__((address_space(1))) unsigned int as1_u32;
typedef __attribute__((address_space(3))) unsigned int as3_u32;

// async global->LDS, 16B per lane, dest = uniform base + lane*16
__device__ __forceinline__ void async_copy16(const void* g, void* l) {
  __builtin_amdgcn_global_load_lds((const as1_u32*)g, (as3_u32*)l, 16, 0, 0);
}

__device__ __forceinline__ unsigned short f2bf(float f) {  // RNE float->bf16 bits
  union { float f; unsigned u; } v; v.f = f;
  unsigned r = v.u + 0x7fffu + ((v.u >> 16) & 1u);
  return (unsigned short)(r >> 16);
}

__device__ __forceinline__ floatx4 mfma_bf16(bf16x8 a, bf16x8 b, floatx4 c) {
  return __builtin_amdgcn_mfma_f32_16x16x32_bf16(a, b, c, 0, 0, 0);
}

__device__ __forceinline__ floatx16 mfma32(bf16x8 a, bf16x8 b, floatx16 c) {
  return __builtin_amdgcn_mfma_f32_32x32x16_bf16(a, b, c, 0, 0, 0);
}

__device__ __forceinline__ bf16x8 lds_frag(const unsigned short* p) {
  return *(const bf16x8*)(const void*)p;  // ds_read_b128
}

// ---- prep: all four f32->bf16 conversions in ONE launch --------------------
__global__ __launch_bounds__(256)
void prep(const float* __restrict__ x,  const float* __restrict__ wq,
          const float* __restrict__ wk, const float* __restrict__ wv,
          unsigned short* __restrict__ Xb, unsigned short* __restrict__ Wqb,
          unsigned short* __restrict__ Wkb, unsigned short* __restrict__ Wvb) {
  const int i = blockIdx.x * 256 + threadIdx.x;
  const float* s; unsigned short* d; int off;
  if (i < 2097152)             { s = x;  d = Xb;  off = i; }
  else if (i < 2097152+65536)  { s = wq; d = Wqb; off = i - 2097152; }
  else if (i < 2097152+131072) { s = wk; d = Wkb; off = i - (2097152+65536); }
  else                         { s = wv; d = Wvb; off = i - (2097152+131072); }
  const float4 v = ((const float4*)s)[off];
  ushort4v o;
  o.x = f2bf(v.x); o.y = f2bf(v.y); o.z = f2bf(v.z); o.w = f2bf(v.w);
  *(ushort4v*)(void*)(d + (size_t)off * 4) = o;
}

// ---- fused QKV GEMM: unchanged (verified) ----------------------------------
__global__ __launch_bounds__(256, 2)
void gemm_qkv(const unsigned short* __restrict__ Xb,
              const unsigned short* __restrict__ Wqb,
              const unsigned short* __restrict__ Wkb,
              const unsigned short* __restrict__ Wvb,
              unsigned short* __restrict__ Q,
              unsigned short* __restrict__ K,
              unsigned short* __restrict__ Vt) {
  const int gid = blockIdx.x;
  const unsigned short *A, *B; unsigned short* C;
  int m0, n0, N;
  if (gid < 512) {                        // Q = Xb · Wq^T
    A = Xb; B = Wqb; C = Q; N = 512;
    m0 = (gid & 127) * 128; n0 = (gid >> 7) * 128;
  } else if (gid < 1024) {                // K = Xb · Wk^T
    A = Xb; B = Wkb; C = K; N = 512;
    m0 = ((gid - 512) & 127) * 128; n0 = ((gid - 512) >> 7) * 128;
  } else {                                // V^T = Wv · Xb^T  (M=512, N=16384)
    A = Wvb; B = Xb; C = Vt; N = 16384;
    m0 = ((gid - 1024) & 3) * 128; n0 = ((gid - 1024) >> 2) * 128;
  }

  __shared__ unsigned short As[128 * 64];
  __shared__ unsigned short Bs[128 * 64];
  const int tid = threadIdx.x;
  const int w = tid >> 6, lane = tid & 63;
  const int quad = lane >> 4, l15 = lane & 15;
  const int wm = w >> 1, wn = w & 1;
  const int row_l = lane >> 3;
  const int chk   = lane & 7;
  const int s_chk = chk ^ row_l;          // swizzled SOURCE chunk

  floatx4 acc[16];
#pragma unroll
  for (int i = 0; i < 16; i++) acc[i] = (floatx4){0.f, 0.f, 0.f, 0.f};

  for (int kt = 0; kt < 8; kt++) {
    __syncthreads();
#pragma unroll
    for (int i = 0; i < 4; i++) {
      const int c = w * 4 + i;
      const int row = c * 8 + row_l;
      async_copy16(A + (size_t)(m0 + row) * 512 + kt * 64 + s_chk * 8, &As[c * 512]);
      async_copy16(B + (size_t)(n0 + row) * 512 + kt * 64 + s_chk * 8, &Bs[c * 512]);
    }
    __syncthreads();
#pragma unroll
    for (int kc = 0; kc < 2; kc++) {
      bf16x8 af[4], bfv[4];
#pragma unroll
      for (int i = 0; i < 4; i++) {
        const int pc = ((kc * 4 + quad) ^ (l15 & 7)) * 8;
        af[i]  = lds_frag(&As[(wm * 64 + i * 16 + l15) * 64 + pc]);
        bfv[i] = lds_frag(&Bs[(wn * 64 + i * 16 + l15) * 64 + pc]);
      }
#pragma unroll
      for (int mi = 0; mi < 4; mi++)
#pragma unroll
        for (int ni = 0; ni < 4; ni++)
          acc[mi * 4 + ni] = mfma_bf16(af[mi], bfv[ni], acc[mi * 4 + ni]);
    }
  }
#pragma unroll
  for (int mi = 0; mi < 4; mi++)
#pragma unroll
    for (int ni = 0; ni < 4; ni++)
#pragma unroll
      for (int r = 0; r < 4; r++) {
        const int row = m0 + wm * 64 + mi * 16 + quad * 4 + r;
        const int col = n0 + wn * 64 + ni * 16 + l15;
        C[(size_t)row * N + col] = f2bf(acc[mi * 4 + ni][r]);
      }
}

// ---- fused attention: R9 + merged mega-phase + full bank hash (round 15 =
// round 14, resubmitted after infra timeout; kernel never ran) ---------------
// Evidence R13: conflicts 2.1e7->4.2e6 without K/V LDS => ~1.7e7 from K/V/Pb
// fragment reads; R4==R9 time => LDS volume not binding. Fix 1: bank hash
// bh(r)=((r&7)+(r>>3))&7 (old &7-only left rows 8 apart colliding 4-way),
// applied BOTH sides (DMA pre-swizzled source + read). Fix 2: merge PV(kt)
// with QK^T(kt+1) into one 32-MFMA mega-phase: 4 barriers/step (was 5), two
// independent MFMA+ds_read streams, DMA issued after B2a with max cover.
// Per-element FP order unchanged from R9 -> absmax oracle 4.88e-4 exactly.
#define SCALE 0.044194173824159216f  // 1/sqrt(512)

__global__ __launch_bounds__(512, 1)
void attn_kernel(const unsigned short* __restrict__ Qg,
                 const unsigned short* __restrict__ Kg,
                 const unsigned short* __restrict__ Vt,   // [512][16384] = V^T
                 float* __restrict__ O) {                 // f32 output
  __shared__ unsigned short Ks[64 * 512];   // 64 KB (hash-swizzled)
  __shared__ unsigned short Vs[512 * 64];   // 64 KB (hash-swizzled)
  __shared__ float Sx[64][65];              // 16.6 KB
  __shared__ unsigned short Pb[64 * 64];    //  8 KB (hash-swizzled)
  __shared__ float m_row[64], l_row[64], a_row[64];

  const int tid = threadIdx.x;
  const int w = tid >> 6, lane = tid & 63;
  const int l31 = lane & 31, lh = lane >> 5;

  // XCD-contiguous swizzle
  const int g0 = blockIdx.x;
  const int g  = (g0 & 7) * 32 + (g0 >> 3);   // 256 blocks, bijective
  const int b  = g >> 6;
  const int q0 = (g & 63) * 64;

  const int t  = w & 3;          // QK^T: q-half t>>1, key-half t&1
  const int gk = w >> 2;         // QK^T: feature-half
  const int p2 = w >> 2, dbase = (w & 3) * 128;  // PV roles (R9)

  const unsigned short* kb0 = Kg + (size_t)b * 4096 * 512;
  const unsigned short* vb0 = Vt + (size_t)b * 4096;
  const int v_d = lane >> 3;

  // K tile stage: row = w*8+u; bh(row) = (u+w)&7; phys chunk p holds logical
  // p^bh(row) -> pre-swizzled source.
  auto issue_K = [&](int kt_) {
#pragma unroll
    for (int u = 0; u < 8; u++) {
      const int row = w * 8 + u;
      const int hk = (u + w) & 7;
      async_copy16(kb0 + ((size_t)kt_ * 64 + row) * 512 + (lane ^ hk) * 8,
                   &Ks[row * 512]);
    }
  };
  // V tile stage: d = w*64+u*8+v_d; bh(d) = (v_d+u)&7 (8w==0 mod 8).
  auto issue_V = [&](int kt_) {
#pragma unroll
    for (int u = 0; u < 8; u++) {
      const int d = w * 64 + u * 8 + v_d;
      const int hv = (v_d + u) & 7;
      async_copy16(vb0 + (size_t)kt_ * 64 + (size_t)d * 16384 + ((lane & 7) ^ hv) * 8,
                   &Vs[(w * 64 + u * 8) * 64]);
    }
  };

  issue_K(0);   // earliest possible

  if (tid < 64) { m_row[tid] = -3.0e38f; l_row[tid] = 0.f; }

  // Q A-fragments: 32 q-rows x 256 feats per wave (64 VGPR; R9 verbatim)
  bf16x8 qf[16];
  {
    const unsigned short* qrow =
        Qg + (size_t)(b * 4096 + q0 + (t >> 1) * 32 + l31) * 512;
#pragma unroll
    for (int i = 0; i < 16; i++)
      qf[i] = *(const bf16x8*)(const void*)(qrow + gk * 256 + i * 16 + lh * 8);
  }

  floatx16 oacc[4];
#pragma unroll
  for (int j = 0; j < 4; j++)
#pragma unroll
    for (int r = 0; r < 16; r++) oacc[j][r] = 0.f;

  const int krow = (t & 1) * 32 + l31;                 // QK^T B-row
  const int hKr  = ((krow & 7) + (krow >> 3)) & 7;     // bh(krow)
  const int srow = tid >> 3, sg = tid & 7;
  const int pb_wc = sg ^ (((srow & 7) + (srow >> 3)) & 7);  // Pb write chunk
  const int pq   = p2 * 32 + l31;                      // P A-row
  const int hPq  = ((pq & 7) + (pq >> 3)) & 7;         // bh(pq)

  bf16x8 pfr[4];

  // ===== prologue: QK^T(0) -> softmax(0) -> pfr(0) ==========================
  asm volatile("s_waitcnt vmcnt(0)" ::: "memory");
  __builtin_amdgcn_sched_barrier(0);
  __syncthreads();                 // Ks(0) + qf resident
  issue_V(0);

  {
    floatx16 sa, sb;
#pragma unroll
    for (int r = 0; r < 16; r++) { sa[r] = 0.f; sb[r] = 0.f; }
#pragma unroll
    for (int i = 0; i < 16; i += 2) {
      bf16x8 k0 = lds_frag(&Ks[krow * 512 + (((gk * 32 + i * 2 + lh) ^ hKr) * 8)]);
      sa = mfma32(qf[i], k0, sa);
      bf16x8 k1 = lds_frag(&Ks[krow * 512 + (((gk * 32 + i * 2 + 2 + lh) ^ hKr) * 8)]);
      sb = mfma32(qf[i + 1], k1, sb);
    }
#pragma unroll
    for (int r = 0; r < 16; r++) sa[r] += sb[r];
    if (w < 4) {
#pragma unroll
      for (int reg = 0; reg < 16; reg++) {
        const int rl = (reg & 3) + 8 * (reg >> 2) + 4 * lh;
        Sx[(t >> 1) * 32 + rl][(t & 1) * 32 + l31] = sa[reg];
      }
    }
    __syncthreads();               // B2a
    if (w >= 4) {
#pragma unroll
      for (int reg = 0; reg < 16; reg++) {
        const int rl = (reg & 3) + 8 * (reg >> 2) + 4 * lh;
        float* p = &Sx[(t >> 1) * 32 + rl][(t & 1) * 32 + l31];
        *p = (*p + sa[reg]) * SCALE;
      }
    }
    issue_K(1);                    // Ks(0) dead (all QK^T reads pre-B2a)
  }
  __syncthreads();                 // B2b: Sx(0) final

  // softmax + pfr/rescale shared with the main loop via lambdas.
  auto softmax_step = [&]() {
    float vals[8];
    float tmax = -3.0e38f;
#pragma unroll
    for (int j = 0; j < 8; j++) {
      float xv = Sx[srow][sg * 8 + j];
      xv = fminf(fmaxf(xv, -1.0e4f), 1.0e4f);
      vals[j] = xv;
      tmax = fmaxf(tmax, xv);
    }
    tmax = fmaxf(tmax, __shfl_xor(tmax, 1));
    tmax = fmaxf(tmax, __shfl_xor(tmax, 2));
    tmax = fmaxf(tmax, __shfl_xor(tmax, 4));
    const float m_old = m_row[srow];
    const float m_new = fmaxf(m_old, tmax);
    const float alpha = __expf(m_old - m_new);
    float lsum = 0.f;
    short8 pvec;
#pragma unroll
    for (int j = 0; j < 8; j++) {
      const float p = __expf(vals[j] - m_new);
      lsum += p;
      pvec[j] = (short)f2bf(p);
    }
    lsum += __shfl_xor(lsum, 1);
    lsum += __shfl_xor(lsum, 2);
    lsum += __shfl_xor(lsum, 4);
    *(short8*)(void*)&Pb[srow * 64 + pb_wc * 8] = pvec;
    if (sg == 0) {
      m_row[srow] = m_new;
      l_row[srow] = l_row[srow] * alpha + lsum;
      a_row[srow] = alpha;
    }
  };
  auto prep_pv = [&]() {           // rescale oacc + load P A-frags
#pragma unroll
    for (int reg = 0; reg < 16; reg++) {
      const float a = a_row[p2 * 32 + (reg & 3) + 8 * (reg >> 2) + 4 * lh];
#pragma unroll
      for (int j = 0; j < 4; j++) oacc[j][reg] *= a;
    }
#pragma unroll
    for (int kk = 0; kk < 4; kk++)
      pfr[kk] = lds_frag(&Pb[pq * 64 + (((kk * 2 + lh) ^ hPq) * 8)]);
  };

  softmax_step();                  // softmax(0)
  __syncthreads();                 // B3
  prep_pv();                       // pfr(0), alpha(0) rescale (oacc==0)

  // ===== main loop: PV(kt) + QK^T(kt+1) mega-phase ==========================
  for (int kt = 0; kt < 63; kt++) {
    asm volatile("s_waitcnt vmcnt(0)" ::: "memory");
    __builtin_amdgcn_sched_barrier(0);
    __syncthreads();               // B_pub: Vs(kt) + Ks(kt+1) resident

    floatx16 sa, sb;
#pragma unroll
    for (int r = 0; r < 16; r++) { sa[r] = 0.f; sb[r] = 0.f; }
#pragma unroll
    for (int i = 0; i < 16; i += 2) {
      // QK^T(kt+1) pair
      bf16x8 k0 = lds_frag(&Ks[krow * 512 + (((gk * 32 + i * 2 + lh) ^ hKr) * 8)]);
      sa = mfma32(qf[i], k0, sa);
      // PV(kt) u = i   (j = u>>2, kk = u&3; R9 j-major order)
      {
        const int j = i >> 2, kk = i & 3;
        const int d = dbase + j * 32 + l31;
        const int hV = ((d & 7) + (d >> 3)) & 7;
        bf16x8 vfr = lds_frag(&Vs[d * 64 + (((kk * 2 + lh) ^ hV) * 8)]);
        oacc[j] = mfma32(pfr[kk], vfr, oacc[j]);
      }
      bf16x8 k1 = lds_frag(&Ks[krow * 512 + (((gk * 32 + i * 2 + 2 + lh) ^ hKr) * 8)]);
      sb = mfma32(qf[i + 1], k1, sb);
      // PV(kt) u = i+1
      {
        const int u = i + 1;
        const int j = u >> 2, kk = u & 3;
        const int d = dbase + j * 32 + l31;
        const int hV = ((d & 7) + (d >> 3)) & 7;
        bf16x8 vfr = lds_frag(&Vs[d * 64 + (((kk * 2 + lh) ^ hV) * 8)]);
        oacc[j] = mfma32(pfr[kk], vfr, oacc[j]);
      }
    }
#pragma unroll
    for (int r = 0; r < 16; r++) sa[r] += sb[r];

    if (w < 4) {                   // writer half: raw partial (kt+1)
#pragma unroll
      for (int reg = 0; reg < 16; reg++) {
        const int rl = (reg & 3) + 8 * (reg >> 2) + 4 * lh;
        Sx[(t >> 1) * 32 + rl][(t & 1) * 32 + l31] = sa[reg];
      }
    }
    __syncthreads();               // B2a: partials visible; Ks+Vs reads done
    if (w >= 4) {                  // adder half: combine + scale (kt+1)
#pragma unroll
      for (int reg = 0; reg < 16; reg++) {
        const int rl = (reg & 3) + 8 * (reg >> 2) + 4 * lh;
        float* p = &Sx[(t >> 1) * 32 + rl][(t & 1) * 32 + l31];
        *p = (*p + sa[reg]) * SCALE;
      }
    }
    issue_V(kt + 1);               // Vs(kt) dead
    if (kt + 2 <= 63) issue_K(kt + 2);   // Ks(kt+1) dead
    __syncthreads();               // B2b: Sx(kt+1) final

    softmax_step();                // softmax(kt+1)
    __syncthreads();               // B3
    prep_pv();                     // pfr(kt+1), rescale by alpha(kt+1)
  }

  // ===== epilogue: PV(63) ====================================================
  asm volatile("s_waitcnt vmcnt(0)" ::: "memory");
  __builtin_amdgcn_sched_barrier(0);
  __syncthreads();                 // Vs(63) resident
#pragma unroll
  for (int u = 0; u < 16; u++) {
    const int j = u >> 2, kk = u & 3;
    const int d = dbase + j * 32 + l31;
    const int hV = ((d & 7) + (d >> 3)) & 7;
    bf16x8 vfr = lds_frag(&Vs[d * 64 + (((kk * 2 + lh) ^ hV) * 8)]);
    oacc[j] = mfma32(pfr[kk], vfr, oacc[j]);
  }

  // ---- O / l, f32 store (R9 verbatim)
  __syncthreads();
#pragma unroll
  for (int reg = 0; reg < 16; reg++) {
    const int rl = (reg & 3) + 8 * (reg >> 2) + 4 * lh;
    const float inv = 1.0f / l_row[p2 * 32 + rl];
    const int row = b * 4096 + q0 + p2 * 32 + rl;
#pragma unroll
    for (int j = 0; j < 4; j++)
      O[(size_t)row * 512 + dbase + j * 32 + l31] = oacc[j][reg] * inv;
  }
}

// ---- launch ---------------------------------------------------------------
extern "C" void kernel_launch(void* const* d_in, const int* in_sizes, int n_in,
                              void* d_out, int out_size, void* d_ws, size_t ws_size,
                              hipStream_t stream) {
  const float* x   = (const float*)d_in[0];
  const float* wqf = (const float*)d_in[1];
  const float* wkf = (const float*)d_in[2];
  const float* wvf = (const float*)d_in[3];

  unsigned short* Xb  = (unsigned short*)d_out;        // 16384 x 512 bf16 (dead before attn)
  unsigned short* Wqb = (unsigned short*)d_ws;         // 512 x 512
  unsigned short* Wkb = Wqb + (size_t)512 * 512;
  unsigned short* Wvb = Wkb + (size_t)512 * 512;
  unsigned short* Q   = Wvb + (size_t)512 * 512;       // 16384 x 512
  unsigned short* K   = Q + (size_t)16384 * 512;       // 16384 x 512
  unsigned short* Vt  = K + (size_t)16384 * 512;       // 512 x 16384 (V^T)

  prep<<<dim3(8960), 256, 0, stream>>>(x, wqf, wkf, wvf, Xb, Wqb, Wkb, Wvb);
  gemm_qkv<<<dim3(1536), 256, 0, stream>>>(Xb, Wqb, Wkb, Wvb, Q, K, Vt);
  attn_kernel<<<dim3(256), 512, 0, stream>>>(Q, K, Vt, (float*)d_out);
}